// Round 20
// baseline (177.931 us; speedup 1.0000x reference)
//
#include <hip/hip_runtime.h>
#include <hip/hip_bf16.h>

// Problem: B=2, S=2048, D=768, H=12, HD=64. fp32 in/out, bf16 MFMA inside.
// r20 = r19 champion (175.7us) + GEMM2 register-prefetch double-buffer:
// GEMM2's 768 blocks are ALL co-resident (8KB LDS, ~64 VGPR), so its time is
// the serial 12-iteration K-loop critical path (stage -> drain barrier ->
// 4 MFMA -> barrier). The attn-r4 dbuf pattern (prefetch next tile into
// registers during compute, commit, ONE barrier/iter) hides the stage
// latency — the one GEMM where the "dbuf is neutral" ledger doesn't apply.
#define B_ 2
#define S_ 2048
#define D_ 768
#define H_ 12
#define HD_ 64
#define EXP2C_ 0.1803368801111244f  // SCALE * log2(e), folded into Q

typedef __attribute__((ext_vector_type(8))) short bf16x8;
typedef __attribute__((ext_vector_type(8))) unsigned short u16x8;
typedef __attribute__((ext_vector_type(4))) float f32x4;

static __device__ __forceinline__ unsigned short f2bf(float x) {
    union { float f; unsigned u; } v; v.f = x;
    unsigned r = (v.u + 0x7FFFu + ((v.u >> 16) & 1u)) >> 16;  // RNE
    return (unsigned short)r;
}
static __device__ __forceinline__ float bf2f(unsigned short h) {
    union { unsigned u; float f; } v; v.u = ((unsigned)h) << 16;
    return v.f;
}
static __device__ __forceinline__ float fexp2(float x) { return __builtin_exp2f(x); }

// packed f32x2 -> bf16x2 (v_cvt_pk_bf16_f32) as raw u32
static __device__ __forceinline__ unsigned pk_bf16(float a, float b) {
    __hip_bfloat162 pk = __float22bfloat162_rn(make_float2(a, b));
    union { __hip_bfloat162 h; unsigned u; } v; v.h = pk;
    return v.u;
}

static __device__ __forceinline__ f32x4 mfma32(bf16x8 a, bf16x8 b, f32x4 c) {
    return __builtin_amdgcn_mfma_f32_16x16x32_bf16(a, b, c, 0, 0, 0);
}

// async global->LDS, 16B/lane; LDS dest = wave-uniform base + lane*16 (m97)
typedef __attribute__((address_space(3))) unsigned int lds_u32;
typedef __attribute__((address_space(1))) const unsigned int glb_u32;
static __device__ __forceinline__ void glds16(const unsigned short* g, unsigned short* l) {
    __builtin_amdgcn_global_load_lds((glb_u32*)g, (lds_u32*)l, 16, 0, 0);
}

// ---------------------------------------------------------------------------
// Merged prep: conv x->bf16 | transpose w_qkv | transpose w_proj.
// ---------------------------------------------------------------------------
#define PREP_CONV_ 1536   // 4096*768/(256*8)
#define PREP_TQKV_ 1728   // (2304/32)*(768/32)
#define PREP_TPRJ_ 576    // (768/32)*(768/32)
__global__ __launch_bounds__(256) void prep_kernel(
    const float* __restrict__ x,      unsigned short* __restrict__ x16,
    const float* __restrict__ w_qkv,  unsigned short* __restrict__ wqkvT,
    const float* __restrict__ w_proj, unsigned short* __restrict__ wprojT)
{
    __shared__ float tile[32][33];
    const int bid = blockIdx.x, t = threadIdx.x;
    if (bid < PREP_CONV_) {
        const int i = (bid * 256 + t) * 8;
        float4 a0 = *(const float4*)(x + i);
        float4 a1 = *(const float4*)(x + i + 4);
        u16x8 s;
        s[0] = f2bf(a0.x); s[1] = f2bf(a0.y); s[2] = f2bf(a0.z); s[3] = f2bf(a0.w);
        s[4] = f2bf(a1.x); s[5] = f2bf(a1.y); s[6] = f2bf(a1.z); s[7] = f2bf(a1.w);
        *(u16x8*)(x16 + i) = s;
        return;
    }
    const float* w; unsigned short* wT; int N, bb;
    if (bid < PREP_CONV_ + PREP_TQKV_) { w = w_qkv; wT = wqkvT; N = 3 * D_; bb = bid - PREP_CONV_; }
    else                               { w = w_proj; wT = wprojT; N = D_;   bb = bid - PREP_CONV_ - PREP_TQKV_; }
    const int K = D_;
    const int nt = N / 32;
    const int n0 = (bb % nt) * 32, k0 = (bb / nt) * 32;
    const int tx = t & 31, ty = t >> 5;
#pragma unroll
    for (int i = 0; i < 4; i++)
        tile[ty + i * 8][tx] = w[(size_t)(k0 + ty + i * 8) * N + n0 + tx];
    __syncthreads();
#pragma unroll
    for (int i = 0; i < 4; i++)
        wT[(size_t)(n0 + ty + i * 8) * K + k0 + tx] = f2bf(tile[tx][ty + i * 8]);
}

// ---------------------------------------------------------------------------
// GEMM1 (r18 champion): 128x96 tile, BK=32, glds16 staging, 768 blocks =
// exactly 3/CU. Ledger: 64x128 (r16) doubles weight re-reads — BAD;
// BK=64 (r12) halves blocks/CU — BAD.
// ---------------------------------------------------------------------------
template <int BM, int BN, bool OUT_F32>
__global__ __launch_bounds__(256) void gemm_bt_kernel(
    const unsigned short* __restrict__ A,
    const unsigned short* __restrict__ Bt,
    const float* __restrict__ bias,
    void* __restrict__ Cp,
    int M, int N, int K)
{
    __shared__ __align__(16) unsigned short As[BM][32];
    __shared__ __align__(16) unsigned short Bs[BN][32];
    constexpr int MI = BM / 32, NJ = BN / 32;
    constexpr int ACH = BM * 4, BCH = BN * 4;

    const int t = threadIdx.x;
    const int w = t >> 6, lane = t & 63, quad = lane >> 4, l16 = lane & 15;
    const int n0 = blockIdx.x * BN, m0 = blockIdx.y * BM;
    const int mw = (w & 1) * (BM / 2), nw = (w >> 1) * (BN / 2);

    const f32x4 z = {0.f, 0.f, 0.f, 0.f};
    f32x4 acc[MI][NJ];
#pragma unroll
    for (int i = 0; i < MI; i++)
#pragma unroll
        for (int j = 0; j < NJ; j++) acc[i][j] = z;

    for (int kk = 0; kk < K; kk += 32) {
#pragma unroll
        for (int it = 0; it < (ACH + 255) / 256; it++) {
            const int c = t + it * 256;
            if (ACH % 256 == 0 || c < ACH) {
                const int row = c >> 2, c8 = (c & 3) << 3;
                glds16(A + (size_t)(m0 + row) * K + kk + c8, &As[0][0] + c * 8);
            }
        }
#pragma unroll
        for (int it = 0; it < (BCH + 255) / 256; it++) {
            const int c = t + it * 256;
            if (BCH % 256 == 0 || c < BCH) {
                const int row = c >> 2, c8 = (c & 3) << 3;
                glds16(Bt + (size_t)(n0 + row) * K + kk + c8, &Bs[0][0] + c * 8);
            }
        }
        __syncthreads();

        bf16x8 a[MI], b[NJ];
#pragma unroll
        for (int i = 0; i < MI; i++)
            a[i] = *(const bf16x8*)(&As[mw + i * 16 + l16][quad * 8]);
#pragma unroll
        for (int j = 0; j < NJ; j++)
            b[j] = *(const bf16x8*)(&Bs[nw + j * 16 + l16][quad * 8]);
#pragma unroll
        for (int i = 0; i < MI; i++)
#pragma unroll
            for (int j = 0; j < NJ; j++)
                acc[i][j] = mfma32(a[i], b[j], acc[i][j]);
        __syncthreads();
    }

#pragma unroll
    for (int j = 0; j < NJ; j++) {
        const int col = n0 + nw + j * 16 + l16;
        const float bv = bias[col];
#pragma unroll
        for (int i = 0; i < MI; i++) {
#pragma unroll
            for (int r = 0; r < 4; r++) {
                const int row = m0 + mw + i * 16 + quad * 4 + r;
                const float v = acc[i][j][r] + bv;
                if (OUT_F32) ((float*)Cp)[(size_t)row * N + col] = v;
                else         ((unsigned short*)Cp)[(size_t)row * N + col] = f2bf(v);
            }
        }
    }
}

// ---------------------------------------------------------------------------
// GEMM2 v2 (r20): 64x64 tile, register-prefetch double-buffered K-loop.
// All 768 blocks co-resident -> duration = serial K-loop path; prefetching
// the next A/B tiles into registers during the current tile's MFMA hides
// the global-load latency; ONE barrier per iteration (attn-r4 pattern,
// measured 2x there). LDS 16KB (2 bufs) — still fully co-resident.
// ---------------------------------------------------------------------------
__global__ __launch_bounds__(256) void gemm2_dbuf_kernel(
    const unsigned short* __restrict__ A,    // [M][K] bf16
    const unsigned short* __restrict__ Bt,   // [N][K] bf16
    const float* __restrict__ bias,
    float* __restrict__ C,                   // [M][N] fp32
    int M, int N, int K)
{
    __shared__ __align__(16) unsigned short As[2][64][32];
    __shared__ __align__(16) unsigned short Bs[2][64][32];

    const int t = threadIdx.x;
    const int w = t >> 6, lane = t & 63, quad = lane >> 4, l16 = lane & 15;
    const int n0 = blockIdx.x * 64, m0 = blockIdx.y * 64;
    const int mw = (w & 1) * 32, nw = (w >> 1) * 32;
    const int srow = t >> 2, sc8 = (t & 3) << 3;  // staging: 1 chunk/thread each

    const f32x4 z = {0.f, 0.f, 0.f, 0.f};
    f32x4 acc[2][2] = {{z, z}, {z, z}};

    // initial stage into buffer 0
    *(u16x8*)(&As[0][srow][sc8]) = *(const u16x8*)(A  + (size_t)(m0 + srow) * K + sc8);
    *(u16x8*)(&Bs[0][srow][sc8]) = *(const u16x8*)(Bt + (size_t)(n0 + srow) * K + sc8);
    __syncthreads();

    const int NKT = K / 32;  // 24 for K=768... (12 for GEMM2's K? K=768 -> 24)
    for (int kt = 0; kt < NKT; kt++) {
        const int buf = kt & 1;
        const bool pre = (kt + 1 < NKT);

        u16x8 pa, pb;
        if (pre) {
            const int ko = (kt + 1) * 32;
            pa = *(const u16x8*)(A  + (size_t)(m0 + srow) * K + ko + sc8);
            pb = *(const u16x8*)(Bt + (size_t)(n0 + srow) * K + ko + sc8);
        }

        bf16x8 a[2], b[2];
#pragma unroll
        for (int i = 0; i < 2; i++)
            a[i] = *(const bf16x8*)(&As[buf][mw + i * 16 + l16][quad * 8]);
#pragma unroll
        for (int j = 0; j < 2; j++)
            b[j] = *(const bf16x8*)(&Bs[buf][nw + j * 16 + l16][quad * 8]);
#pragma unroll
        for (int i = 0; i < 2; i++)
#pragma unroll
            for (int j = 0; j < 2; j++)
                acc[i][j] = mfma32(a[i], b[j], acc[i][j]);

        if (pre) {
            *(u16x8*)(&As[buf ^ 1][srow][sc8]) = pa;
            *(u16x8*)(&Bs[buf ^ 1][srow][sc8]) = pb;
        }
        __syncthreads();
    }

#pragma unroll
    for (int j = 0; j < 2; j++) {
        const int col = n0 + nw + j * 16 + l16;
        const float bv = bias[col];
#pragma unroll
        for (int i = 0; i < 2; i++) {
#pragma unroll
            for (int r = 0; r < 4; r++) {
                const int row = m0 + mw + i * 16 + quad * 4 + r;
                C[(size_t)row * N + col] = acc[i][j][r] + bv;
            }
        }
    }
}

// ---------------------------------------------------------------------------
// Repack V (r10, measured good): LDS-tiled transpose, coalesced both sides.
// ---------------------------------------------------------------------------
__global__ __launch_bounds__(256) void repack_v_kernel(
    const unsigned short* __restrict__ qkv,
    unsigned short* __restrict__ vt)
{
    __shared__ unsigned short T[64][65];
    const int t = threadIdx.x;
    const int bh = blockIdx.x, st = blockIdx.y;
    const int b = bh / H_, h = bh % H_;
    const unsigned short* src =
        qkv + (size_t)(b * S_ + st * 64) * (3 * D_) + 2 * D_ + h * HD_;

#pragma unroll
    for (int it = 0; it < 2; it++) {
        const int c = t + it * 256, sr = c >> 3, g = c & 7;
        u16x8 v = *(const u16x8*)(src + (size_t)sr * (3 * D_) + g * 8);
#pragma unroll
        for (int j = 0; j < 8; j++) T[sr][g * 8 + j] = v[j];
    }
    __syncthreads();
#pragma unroll
    for (int it = 0; it < 2; it++) {
        const int c = t + it * 256, hd = c >> 3, g = c & 7;
        u16x8 v;
#pragma unroll
        for (int j = 0; j < 8; j++) v[j] = T[g * 8 + j][hd];
        *(u16x8*)(vt + (size_t)(bh * HD_ + hd) * S_ + st * 64 + g * 8) = v;
    }
}

// ---------------------------------------------------------------------------
// Flash attention — r19 CHAMPION, verbatim (64.4us, conflicts=0, LDS 40960 =
// 4 blocks/CU, VGPR 64). Ledger (do not revisit): r7 mfma16, r8 wave-split,
// r11 32x32 MFMA, r12 BK=64, r14 r5-math revert, r20-considered 512-thread
// block (1.33x makespan imbalance > staging savings).
// ---------------------------------------------------------------------------
__global__ __launch_bounds__(256) void attn_kernel(
    const unsigned short* __restrict__ qkv,  // [B*S][3*D] bf16
    const unsigned short* __restrict__ vt,   // [B*H][HD][S] bf16
    unsigned short* __restrict__ o)          // [B*S][D] bf16
{
    __shared__ __align__(16) unsigned short Ks[2][64][64];   // [key][hd] xor-swizzled
    __shared__ __align__(16) unsigned short Vs[2][64][64];   // [hd][key] xor-swizzled
    __shared__ __align__(16) unsigned short p_lds[4][16][64];// xor-swizzled, no pad

    const int t = threadIdx.x;
    const int w = t >> 6, lane = t & 63, quad = lane >> 4, l16 = lane & 15;
    const int h8 = l16 & 7;
    const int qt = blockIdx.x, bh = blockIdx.y;
    const int b = bh / H_, h = bh % H_;
    const int ld = 3 * D_;  // 2304

    // Q A-frags (m=l16, k=quad*8+j), prescaled by SCALE*log2e
    const unsigned short* qbase =
        qkv + (size_t)(b * S_ + qt * 64 + 16 * w + l16) * ld + h * HD_;
    u16x8 qr0 = *(const u16x8*)(qbase + quad * 8);
    u16x8 qr1 = *(const u16x8*)(qbase + 32 + quad * 8);
    bf16x8 qf0, qf1;
#pragma unroll
    for (int j = 0; j < 8; j++) {
        qf0[j] = (short)f2bf(bf2f(qr0[j]) * EXP2C_);
        qf1[j] = (short)f2bf(bf2f(qr1[j]) * EXP2C_);
    }

    const unsigned short* kbase = qkv + (size_t)(b * S_) * ld + D_ + h * HD_;
    const unsigned short* vbase = vt + (size_t)bh * HD_ * S_;

    const f32x4 z = {0.f, 0.f, 0.f, 0.f};
    f32x4 o_acc[4] = {z, z, z, z};
    f32x4 l4[4] = {z, z, z, z};

    // stage tile 0 (16B group g of row stored at g^(row&7))
#pragma unroll
    for (int it = 0; it < 2; it++) {
        const int c = t + it * 256, row = c >> 3, g = c & 7, sg = g ^ (row & 7);
        *(u16x8*)(&Ks[0][row][sg * 8]) = *(const u16x8*)(kbase + (size_t)row * ld + g * 8);
        *(u16x8*)(&Vs[0][row][sg * 8]) = *(const u16x8*)(vbase + (size_t)row * S_ + g * 8);
    }
    __syncthreads();

    const int NT = S_ / 64;  // 32
    for (int kt = 0; kt < NT; kt++) {
        const int buf = kt & 1;
        const bool pre = (kt + 1 < NT);

        u16x8 pk[2], pv[2];
        if (pre) {
            const int kr1 = (kt + 1) * 64;
#pragma unroll
            for (int i = 0; i < 2; i++) {
                const int c = t + i * 256, row = c >> 3, g = c & 7;
                pk[i] = *(const u16x8*)(kbase + (size_t)(kr1 + row) * ld + g * 8);
                pv[i] = *(const u16x8*)(vbase + (size_t)row * S_ + kr1 + g * 8);
            }
        }

        // S = Q . K^T from LDS (swizzled b128 reads)
        f32x4 s_acc[4] = {z, z, z, z};
#pragma unroll
        for (int nt = 0; nt < 4; nt++) {
            const unsigned short* kr = &Ks[buf][nt * 16 + l16][0];
            bf16x8 k0 = *(const bf16x8*)(kr + (quad ^ h8) * 8);
            bf16x8 k1 = *(const bf16x8*)(kr + ((quad + 4) ^ h8) * 8);
            s_acc[nt] = mfma32(qf0, k0, s_acc[nt]);
            s_acc[nt] = mfma32(qf1, k1, s_acc[nt]);
        }

        // p = exp2(s); vector l-accumulate; packed bf16 cvt; swizzled P store
#pragma unroll
        for (int nt = 0; nt < 4; nt++) {
            f32x4 pv4;
#pragma unroll
            for (int r = 0; r < 4; r++) pv4[r] = fexp2(s_acc[nt][r]);
            l4[nt] += pv4;
            const unsigned u01 = pk_bf16(pv4[0], pv4[1]);
            const unsigned u23 = pk_bf16(pv4[2], pv4[3]);
            const int g = nt * 2 + (l16 >> 3), cw = l16 & 7;
#pragma unroll
            for (int r = 0; r < 4; r++) {
                const int row = quad * 4 + r;
                const unsigned short pv16 =
                    (r == 0) ? (unsigned short)u01 :
                    (r == 1) ? (unsigned short)(u01 >> 16) :
                    (r == 2) ? (unsigned short)u23 :
                               (unsigned short)(u23 >> 16);
                p_lds[w][row][(g ^ (row & 7)) * 8 + cw] = pv16;
            }
        }
        // P A-frags: row l16, col group quad (pa0) / 4+quad (pa1), swizzled
        bf16x8 pa0 = *(const bf16x8*)(&p_lds[w][l16][(quad ^ h8) * 8]);
        bf16x8 pa1 = *(const bf16x8*)(&p_lds[w][l16][((quad + 4) ^ h8) * 8]);

        // O += P . V from LDS (swizzled b128 reads)
#pragma unroll
        for (int nt = 0; nt < 4; nt++) {
            const int row = nt * 16 + l16;
            bf16x8 v0 = *(const bf16x8*)(&Vs[buf][row][(quad ^ h8) * 8]);
            bf16x8 v1 = *(const bf16x8*)(&Vs[buf][row][((quad + 4) ^ h8) * 8]);
            o_acc[nt] = mfma32(pa0, v0, o_acc[nt]);
            o_acc[nt] = mfma32(pa1, v1, o_acc[nt]);
        }

        if (pre) {
#pragma unroll
            for (int i = 0; i < 2; i++) {
                const int c = t + i * 256, row = c >> 3, g = c & 7, sg = g ^ (row & 7);
                *(u16x8*)(&Ks[buf ^ 1][row][sg * 8]) = pk[i];
                *(u16x8*)(&Vs[buf ^ 1][row][sg * 8]) = pv[i];
            }
        }
        __syncthreads();
    }

    // l reduction (cols live on 16 lanes x 4 nt) + normalize + write
#pragma unroll
    for (int r = 0; r < 4; r++) {
        float l = l4[0][r] + l4[1][r] + l4[2][r] + l4[3][r];
        l += __shfl_xor(l, 1, 64); l += __shfl_xor(l, 2, 64);
        l += __shfl_xor(l, 4, 64); l += __shfl_xor(l, 8, 64);
        const float inv = 1.f / l;
        const int row = b * S_ + qt * 64 + 16 * w + quad * 4 + r;
        unsigned short* ob = o + (size_t)row * D_ + h * HD_;
#pragma unroll
        for (int nt = 0; nt < 4; nt++)
            ob[nt * 16 + l16] = f2bf(o_acc[nt][r] * inv);
    }
}

// ---------------------------------------------------------------------------
extern "C" void kernel_launch(void* const* d_in, const int* in_sizes, int n_in,
                              void* d_out, int out_size, void* d_ws, size_t ws_size,
                              hipStream_t stream) {
    const float* x      = (const float*)d_in[0];  // [4096][768]
    const float* w_qkv  = (const float*)d_in[1];  // [768][2304]
    const float* b_qkv  = (const float*)d_in[2];  // [2304]
    const float* w_proj = (const float*)d_in[3];  // [768][768]
    const float* b_proj = (const float*)d_in[4];  // [768]
    float* out = (float*)d_out;                   // [4096][768]

    // ws carve (bf16 elements). x16 ALIASES o: GEMM1 consumes x16 before
    // attn writes o (same stream, sequential).
    unsigned short* qkv    = (unsigned short*)d_ws;                     // 9,437,184
    unsigned short* vtb    = qkv    + (size_t)(B_ * S_) * (3 * D_);     // 3,145,728
    unsigned short* o_x16  = vtb    + (size_t)(B_ * H_) * HD_ * S_;     // 3,145,728
    unsigned short* wqkvT  = o_x16  + (size_t)(B_ * S_) * D_;           // 1,769,472
    unsigned short* wprojT = wqkvT  + (size_t)D_ * (3 * D_);            //   589,824

    dim3 blk(256);
    prep_kernel<<<dim3(PREP_CONV_ + PREP_TQKV_ + PREP_TPRJ_), blk, 0, stream>>>(
        x, o_x16, w_qkv, wqkvT, w_proj, wprojT);
    gemm_bt_kernel<128, 96, false><<<dim3((3 * D_) / 96, (B_ * S_) / 128), blk, 0, stream>>>(
        o_x16, wqkvT, b_qkv, qkv, B_ * S_, 3 * D_, D_);
    repack_v_kernel<<<dim3(B_ * H_, S_ / 64), blk, 0, stream>>>(qkv, vtb);
    attn_kernel<<<dim3(S_ / 64, B_ * H_), blk, 0, stream>>>(qkv, vtb, o_x16);
    gemm2_dbuf_kernel<<<dim3(D_ / 64, (B_ * S_) / 64), blk, 0, stream>>>(
        o_x16, wprojT, b_proj, out, B_ * S_, D_, D_);
}

// Round 21
// 174.112 us; speedup vs baseline: 1.0219x; 1.0219x over previous
//
#include <hip/hip_runtime.h>
#include <hip/hip_bf16.h>

// Problem: B=2, S=2048, D=768, H=12, HD=64. fp32 in/out, bf16 MFMA inside.
// FINAL (r21) = r19 champion verbatim (175.7us best measured; 387.6us round-3
// baseline -> 2.2x). r20's GEMM2 dbuf was neutral-within-noise — reverted.
// Win ledger: r4 LDS staging+dbuf, r5 xor-swizzle, r10 coalesced repack,
// r15 GEMM2 64x64, r18 GEMM1 128x96 (3 blk/CU), r19 attn LDS 40960 (4 blk/CU).
// Failure ledger (do not revisit): r7 mfma16, r8 wave-split, r11 32x32 MFMA,
// r12 BK=64, r9/r13/r14 math micro-opts, r16 GEMM1 64x128, r20 GEMM2 dbuf.
#define B_ 2
#define S_ 2048
#define D_ 768
#define H_ 12
#define HD_ 64
#define EXP2C_ 0.1803368801111244f  // SCALE * log2(e), folded into Q

typedef __attribute__((ext_vector_type(8))) short bf16x8;
typedef __attribute__((ext_vector_type(8))) unsigned short u16x8;
typedef __attribute__((ext_vector_type(4))) float f32x4;

static __device__ __forceinline__ unsigned short f2bf(float x) {
    union { float f; unsigned u; } v; v.f = x;
    unsigned r = (v.u + 0x7FFFu + ((v.u >> 16) & 1u)) >> 16;  // RNE
    return (unsigned short)r;
}
static __device__ __forceinline__ float bf2f(unsigned short h) {
    union { unsigned u; float f; } v; v.u = ((unsigned)h) << 16;
    return v.f;
}
static __device__ __forceinline__ float fexp2(float x) { return __builtin_exp2f(x); }

// packed f32x2 -> bf16x2 (v_cvt_pk_bf16_f32) as raw u32
static __device__ __forceinline__ unsigned pk_bf16(float a, float b) {
    __hip_bfloat162 pk = __float22bfloat162_rn(make_float2(a, b));
    union { __hip_bfloat162 h; unsigned u; } v; v.h = pk;
    return v.u;
}

static __device__ __forceinline__ f32x4 mfma32(bf16x8 a, bf16x8 b, f32x4 c) {
    return __builtin_amdgcn_mfma_f32_16x16x32_bf16(a, b, c, 0, 0, 0);
}

// async global->LDS, 16B/lane; LDS dest = wave-uniform base + lane*16 (m97)
typedef __attribute__((address_space(3))) unsigned int lds_u32;
typedef __attribute__((address_space(1))) const unsigned int glb_u32;
static __device__ __forceinline__ void glds16(const unsigned short* g, unsigned short* l) {
    __builtin_amdgcn_global_load_lds((glb_u32*)g, (lds_u32*)l, 16, 0, 0);
}

// ---------------------------------------------------------------------------
// Merged prep: conv x->bf16 | transpose w_qkv | transpose w_proj.
// ---------------------------------------------------------------------------
#define PREP_CONV_ 1536   // 4096*768/(256*8)
#define PREP_TQKV_ 1728   // (2304/32)*(768/32)
#define PREP_TPRJ_ 576    // (768/32)*(768/32)
__global__ __launch_bounds__(256) void prep_kernel(
    const float* __restrict__ x,      unsigned short* __restrict__ x16,
    const float* __restrict__ w_qkv,  unsigned short* __restrict__ wqkvT,
    const float* __restrict__ w_proj, unsigned short* __restrict__ wprojT)
{
    __shared__ float tile[32][33];
    const int bid = blockIdx.x, t = threadIdx.x;
    if (bid < PREP_CONV_) {
        const int i = (bid * 256 + t) * 8;
        float4 a0 = *(const float4*)(x + i);
        float4 a1 = *(const float4*)(x + i + 4);
        u16x8 s;
        s[0] = f2bf(a0.x); s[1] = f2bf(a0.y); s[2] = f2bf(a0.z); s[3] = f2bf(a0.w);
        s[4] = f2bf(a1.x); s[5] = f2bf(a1.y); s[6] = f2bf(a1.z); s[7] = f2bf(a1.w);
        *(u16x8*)(x16 + i) = s;
        return;
    }
    const float* w; unsigned short* wT; int N, bb;
    if (bid < PREP_CONV_ + PREP_TQKV_) { w = w_qkv; wT = wqkvT; N = 3 * D_; bb = bid - PREP_CONV_; }
    else                               { w = w_proj; wT = wprojT; N = D_;   bb = bid - PREP_CONV_ - PREP_TQKV_; }
    const int K = D_;
    const int nt = N / 32;
    const int n0 = (bb % nt) * 32, k0 = (bb / nt) * 32;
    const int tx = t & 31, ty = t >> 5;
#pragma unroll
    for (int i = 0; i < 4; i++)
        tile[ty + i * 8][tx] = w[(size_t)(k0 + ty + i * 8) * N + n0 + tx];
    __syncthreads();
#pragma unroll
    for (int i = 0; i < 4; i++)
        wT[(size_t)(n0 + ty + i * 8) * K + k0 + tx] = f2bf(tile[tx][ty + i * 8]);
}

// ---------------------------------------------------------------------------
// Pure-bf16 GEMM + bias: C[M][N] = A[M][K] . Bt[N][K]^T + bias[N]
// BMxBN tile, BK=32, 4 waves (each (BM/2)x(BN/2) quadrant), glds16 staging.
// Staging loops guarded for chunk counts not divisible by 256 (wave-uniform
// guard, glds16 rule holds).
// Measured tile space: GEMM1 128x96 (768 blocks = 3/CU balance, r18 win);
// GEMM2 64x64 (768 blocks, r15 win).
// ---------------------------------------------------------------------------
template <int BM, int BN, bool OUT_F32>
__global__ __launch_bounds__(256) void gemm_bt_kernel(
    const unsigned short* __restrict__ A,
    const unsigned short* __restrict__ Bt,
    const float* __restrict__ bias,
    void* __restrict__ Cp,
    int M, int N, int K)
{
    __shared__ __align__(16) unsigned short As[BM][32];
    __shared__ __align__(16) unsigned short Bs[BN][32];
    constexpr int MI = BM / 32, NJ = BN / 32;   // frags per wave quadrant
    constexpr int ACH = BM * 4, BCH = BN * 4;   // 16B chunks per tile

    const int t = threadIdx.x;
    const int w = t >> 6, lane = t & 63, quad = lane >> 4, l16 = lane & 15;
    const int n0 = blockIdx.x * BN, m0 = blockIdx.y * BM;
    const int mw = (w & 1) * (BM / 2), nw = (w >> 1) * (BN / 2);

    const f32x4 z = {0.f, 0.f, 0.f, 0.f};
    f32x4 acc[MI][NJ];
#pragma unroll
    for (int i = 0; i < MI; i++)
#pragma unroll
        for (int j = 0; j < NJ; j++) acc[i][j] = z;

    for (int kk = 0; kk < K; kk += 32) {
#pragma unroll
        for (int it = 0; it < (ACH + 255) / 256; it++) {
            const int c = t + it * 256;
            if (ACH % 256 == 0 || c < ACH) {
                const int row = c >> 2, c8 = (c & 3) << 3;
                glds16(A + (size_t)(m0 + row) * K + kk + c8, &As[0][0] + c * 8);
            }
        }
#pragma unroll
        for (int it = 0; it < (BCH + 255) / 256; it++) {
            const int c = t + it * 256;
            if (BCH % 256 == 0 || c < BCH) {
                const int row = c >> 2, c8 = (c & 3) << 3;
                glds16(Bt + (size_t)(n0 + row) * K + kk + c8, &Bs[0][0] + c * 8);
            }
        }
        __syncthreads();

        bf16x8 a[MI], b[NJ];
#pragma unroll
        for (int i = 0; i < MI; i++)
            a[i] = *(const bf16x8*)(&As[mw + i * 16 + l16][quad * 8]);
#pragma unroll
        for (int j = 0; j < NJ; j++)
            b[j] = *(const bf16x8*)(&Bs[nw + j * 16 + l16][quad * 8]);
#pragma unroll
        for (int i = 0; i < MI; i++)
#pragma unroll
            for (int j = 0; j < NJ; j++)
                acc[i][j] = mfma32(a[i], b[j], acc[i][j]);
        __syncthreads();
    }

#pragma unroll
    for (int j = 0; j < NJ; j++) {
        const int col = n0 + nw + j * 16 + l16;
        const float bv = bias[col];
#pragma unroll
        for (int i = 0; i < MI; i++) {
#pragma unroll
            for (int r = 0; r < 4; r++) {
                const int row = m0 + mw + i * 16 + quad * 4 + r;
                const float v = acc[i][j][r] + bv;
                if (OUT_F32) ((float*)Cp)[(size_t)row * N + col] = v;
                else         ((unsigned short*)Cp)[(size_t)row * N + col] = f2bf(v);
            }
        }
    }
}

// ---------------------------------------------------------------------------
// Repack V (r10, measured good): LDS-tiled transpose, coalesced both sides.
// ---------------------------------------------------------------------------
__global__ __launch_bounds__(256) void repack_v_kernel(
    const unsigned short* __restrict__ qkv,
    unsigned short* __restrict__ vt)
{
    __shared__ unsigned short T[64][65];
    const int t = threadIdx.x;
    const int bh = blockIdx.x, st = blockIdx.y;
    const int b = bh / H_, h = bh % H_;
    const unsigned short* src =
        qkv + (size_t)(b * S_ + st * 64) * (3 * D_) + 2 * D_ + h * HD_;

#pragma unroll
    for (int it = 0; it < 2; it++) {
        const int c = t + it * 256, sr = c >> 3, g = c & 7;
        u16x8 v = *(const u16x8*)(src + (size_t)sr * (3 * D_) + g * 8);
#pragma unroll
        for (int j = 0; j < 8; j++) T[sr][g * 8 + j] = v[j];
    }
    __syncthreads();
#pragma unroll
    for (int it = 0; it < 2; it++) {
        const int c = t + it * 256, hd = c >> 3, g = c & 7;
        u16x8 v;
#pragma unroll
        for (int j = 0; j < 8; j++) v[j] = T[g * 8 + j][hd];
        *(u16x8*)(vt + (size_t)(bh * HD_ + hd) * S_ + st * 64 + g * 8) = v;
    }
}

// ---------------------------------------------------------------------------
// Flash attention — r19 CHAMPION (best measured 64.4us; ~64-68 w/ session
// noise): p_lds [4][16][64] xor-swizzled -> LDS 40960 B = 4 blocks/CU,
// conflicts 0, VGPR 64. K/V xor-swizzled dbuf with register prefetch,
// unnormalized softmax (exp2, Q prescaled), deferred l reduction.
// ---------------------------------------------------------------------------
__global__ __launch_bounds__(256) void attn_kernel(
    const unsigned short* __restrict__ qkv,  // [B*S][3*D] bf16
    const unsigned short* __restrict__ vt,   // [B*H][HD][S] bf16
    unsigned short* __restrict__ o)          // [B*S][D] bf16
{
    __shared__ __align__(16) unsigned short Ks[2][64][64];   // [key][hd] xor-swizzled
    __shared__ __align__(16) unsigned short Vs[2][64][64];   // [hd][key] xor-swizzled
    __shared__ __align__(16) unsigned short p_lds[4][16][64];// xor-swizzled, no pad

    const int t = threadIdx.x;
    const int w = t >> 6, lane = t & 63, quad = lane >> 4, l16 = lane & 15;
    const int h8 = l16 & 7;
    const int qt = blockIdx.x, bh = blockIdx.y;
    const int b = bh / H_, h = bh % H_;
    const int ld = 3 * D_;  // 2304

    // Q A-frags (m=l16, k=quad*8+j), prescaled by SCALE*log2e
    const unsigned short* qbase =
        qkv + (size_t)(b * S_ + qt * 64 + 16 * w + l16) * ld + h * HD_;
    u16x8 qr0 = *(const u16x8*)(qbase + quad * 8);
    u16x8 qr1 = *(const u16x8*)(qbase + 32 + quad * 8);
    bf16x8 qf0, qf1;
#pragma unroll
    for (int j = 0; j < 8; j++) {
        qf0[j] = (short)f2bf(bf2f(qr0[j]) * EXP2C_);
        qf1[j] = (short)f2bf(bf2f(qr1[j]) * EXP2C_);
    }

    const unsigned short* kbase = qkv + (size_t)(b * S_) * ld + D_ + h * HD_;
    const unsigned short* vbase = vt + (size_t)bh * HD_ * S_;

    const f32x4 z = {0.f, 0.f, 0.f, 0.f};
    f32x4 o_acc[4] = {z, z, z, z};
    f32x4 l4[4] = {z, z, z, z};

    // stage tile 0 (16B group g of row stored at g^(row&7))
#pragma unroll
    for (int it = 0; it < 2; it++) {
        const int c = t + it * 256, row = c >> 3, g = c & 7, sg = g ^ (row & 7);
        *(u16x8*)(&Ks[0][row][sg * 8]) = *(const u16x8*)(kbase + (size_t)row * ld + g * 8);
        *(u16x8*)(&Vs[0][row][sg * 8]) = *(const u16x8*)(vbase + (size_t)row * S_ + g * 8);
    }
    __syncthreads();

    const int NT = S_ / 64;  // 32
    for (int kt = 0; kt < NT; kt++) {
        const int buf = kt & 1;
        const bool pre = (kt + 1 < NT);

        u16x8 pk[2], pv[2];
        if (pre) {
            const int kr1 = (kt + 1) * 64;
#pragma unroll
            for (int i = 0; i < 2; i++) {
                const int c = t + i * 256, row = c >> 3, g = c & 7;
                pk[i] = *(const u16x8*)(kbase + (size_t)(kr1 + row) * ld + g * 8);
                pv[i] = *(const u16x8*)(vbase + (size_t)row * S_ + kr1 + g * 8);
            }
        }

        // S = Q . K^T from LDS (swizzled b128 reads)
        f32x4 s_acc[4] = {z, z, z, z};
#pragma unroll
        for (int nt = 0; nt < 4; nt++) {
            const unsigned short* kr = &Ks[buf][nt * 16 + l16][0];
            bf16x8 k0 = *(const bf16x8*)(kr + (quad ^ h8) * 8);
            bf16x8 k1 = *(const bf16x8*)(kr + ((quad + 4) ^ h8) * 8);
            s_acc[nt] = mfma32(qf0, k0, s_acc[nt]);
            s_acc[nt] = mfma32(qf1, k1, s_acc[nt]);
        }

        // p = exp2(s); vector l-accumulate; packed bf16 cvt; swizzled P store
#pragma unroll
        for (int nt = 0; nt < 4; nt++) {
            f32x4 pv4;
#pragma unroll
            for (int r = 0; r < 4; r++) pv4[r] = fexp2(s_acc[nt][r]);
            l4[nt] += pv4;
            const unsigned u01 = pk_bf16(pv4[0], pv4[1]);
            const unsigned u23 = pk_bf16(pv4[2], pv4[3]);
            const int g = nt * 2 + (l16 >> 3), cw = l16 & 7;
#pragma unroll
            for (int r = 0; r < 4; r++) {
                const int row = quad * 4 + r;
                const unsigned short pv16 =
                    (r == 0) ? (unsigned short)u01 :
                    (r == 1) ? (unsigned short)(u01 >> 16) :
                    (r == 2) ? (unsigned short)u23 :
                               (unsigned short)(u23 >> 16);
                p_lds[w][row][(g ^ (row & 7)) * 8 + cw] = pv16;
            }
        }
        // P A-frags: row l16, col group quad (pa0) / 4+quad (pa1), swizzled
        bf16x8 pa0 = *(const bf16x8*)(&p_lds[w][l16][(quad ^ h8) * 8]);
        bf16x8 pa1 = *(const bf16x8*)(&p_lds[w][l16][((quad + 4) ^ h8) * 8]);

        // O += P . V from LDS (swizzled b128 reads)
#pragma unroll
        for (int nt = 0; nt < 4; nt++) {
            const int row = nt * 16 + l16;
            bf16x8 v0 = *(const bf16x8*)(&Vs[buf][row][(quad ^ h8) * 8]);
            bf16x8 v1 = *(const bf16x8*)(&Vs[buf][row][((quad + 4) ^ h8) * 8]);
            o_acc[nt] = mfma32(pa0, v0, o_acc[nt]);
            o_acc[nt] = mfma32(pa1, v1, o_acc[nt]);
        }

        if (pre) {
#pragma unroll
            for (int i = 0; i < 2; i++) {
                const int c = t + i * 256, row = c >> 3, g = c & 7, sg = g ^ (row & 7);
                *(u16x8*)(&Ks[buf ^ 1][row][sg * 8]) = pk[i];
                *(u16x8*)(&Vs[buf ^ 1][row][sg * 8]) = pv[i];
            }
        }
        __syncthreads();
    }

    // l reduction (cols live on 16 lanes x 4 nt) + normalize + write
#pragma unroll
    for (int r = 0; r < 4; r++) {
        float l = l4[0][r] + l4[1][r] + l4[2][r] + l4[3][r];
        l += __shfl_xor(l, 1, 64); l += __shfl_xor(l, 2, 64);
        l += __shfl_xor(l, 4, 64); l += __shfl_xor(l, 8, 64);
        const float inv = 1.f / l;
        const int row = b * S_ + qt * 64 + 16 * w + quad * 4 + r;
        unsigned short* ob = o + (size_t)row * D_ + h * HD_;
#pragma unroll
        for (int nt = 0; nt < 4; nt++)
            ob[nt * 16 + l16] = f2bf(o_acc[nt][r] * inv);
    }
}

// ---------------------------------------------------------------------------
extern "C" void kernel_launch(void* const* d_in, const int* in_sizes, int n_in,
                              void* d_out, int out_size, void* d_ws, size_t ws_size,
                              hipStream_t stream) {
    const float* x      = (const float*)d_in[0];  // [4096][768]
    const float* w_qkv  = (const float*)d_in[1];  // [768][2304]
    const float* b_qkv  = (const float*)d_in[2];  // [2304]
    const float* w_proj = (const float*)d_in[3];  // [768][768]
    const float* b_proj = (const float*)d_in[4];  // [768]
    float* out = (float*)d_out;                   // [4096][768]

    // ws carve (bf16 elements). x16 ALIASES o: GEMM1 consumes x16 before
    // attn writes o (same stream, sequential).
    unsigned short* qkv    = (unsigned short*)d_ws;                     // 9,437,184
    unsigned short* vtb    = qkv    + (size_t)(B_ * S_) * (3 * D_);     // 3,145,728
    unsigned short* o_x16  = vtb    + (size_t)(B_ * H_) * HD_ * S_;     // 3,145,728
    unsigned short* wqkvT  = o_x16  + (size_t)(B_ * S_) * D_;           // 1,769,472
    unsigned short* wprojT = wqkvT  + (size_t)D_ * (3 * D_);            //   589,824

    dim3 blk(256);
    prep_kernel<<<dim3(PREP_CONV_ + PREP_TQKV_ + PREP_TPRJ_), blk, 0, stream>>>(
        x, o_x16, w_qkv, wqkvT, w_proj, wprojT);
    gemm_bt_kernel<128, 96, false><<<dim3((3 * D_) / 96, (B_ * S_) / 128), blk, 0, stream>>>(
        o_x16, wqkvT, b_qkv, qkv, B_ * S_, 3 * D_, D_);
    repack_v_kernel<<<dim3(B_ * H_, S_ / 64), blk, 0, stream>>>(qkv, vtb);
    attn_kernel<<<dim3(S_ / 64, B_ * H_), blk, 0, stream>>>(qkv, vtb, o_x16);
    gemm_bt_kernel<64, 64, true><<<dim3(D_ / 64, (B_ * S_) / 64), blk, 0, stream>>>(
        o_x16, wprojT, b_proj, out, B_ * S_, D_, D_);
}